// Round 5
// baseline (861.841 us; speedup 1.0000x reference)
//
#include <hip/hip_runtime.h>
#include <math.h>

using u16 = unsigned short;
typedef __attribute__((ext_vector_type(8))) short short8;
typedef __attribute__((ext_vector_type(4))) float f32x4;

__device__ __forceinline__ float b2f(u16 u) {
    union { unsigned int i; float f; } v; v.i = ((unsigned int)u) << 16; return v.f;
}
__device__ __forceinline__ u16 f2b(float f) {
    union { float f; unsigned int i; } v; v.f = f;
    unsigned int x = v.i;
    return (u16)((x + 0x7FFFu + ((x >> 16) & 1u)) >> 16);
}
// dtype-adaptive external load: fl=1 -> f32, fl=0 -> bf16
__device__ __forceinline__ float ldx(const void* p, long long i, int fl) {
    return fl ? ((const float*)p)[i] : b2f(((const u16*)p)[i]);
}

// ---------------------------------------------------------------------------
// Detect input dtype: read first 4096 u16 of f1 as bf16. flag=1 means f32.
__global__ __launch_bounds__(256) void k_detect(const void* p, int* flag) {
    __shared__ float m[256];
    int t = threadIdx.x;
    const u16* q = (const u16*)p;
    float lm = 0.f;
    for (int j = 0; j < 16; ++j) {
        float v = b2f(q[t * 16 + j]);
        float a = fabsf(v);
        if (!(a <= 1e30f)) a = 1e31f;   // NaN/Inf -> huge
        lm = fmaxf(lm, a);
    }
    m[t] = lm;
    __syncthreads();
    if (t == 0) {
        float mm = 0.f;
        for (int i = 0; i < 256; ++i) mm = fmaxf(mm, m[i]);
        *flag = (mm > 1000.f) ? 1 : 0;
    }
}

// ---------------------------------------------------------------------------
// Weight transpose: conv w (OC=256, IC=256, 3, 3) -> wTo[9][OC][IC] bf16
__global__ __launch_bounds__(256) void k_wt(const void* __restrict__ w,
                                            u16* __restrict__ wTo,
                                            const int* __restrict__ flag) {
    int fl = *flag;
    int idx = blockIdx.x * 256 + threadIdx.x;
    int k  = idx >> 16;          // 0..8
    int oc = (idx >> 8) & 255;
    int ic = idx & 255;
    long long s = (oc * 256 + ic) * 9 + k;
    wTo[idx] = fl ? f2b(((const float*)w)[s]) : ((const u16*)w)[s];
}

// ---------------------------------------------------------------------------
// proj_w transpose: (L=4, C=768, F=256) -> pwT[l][f][c] bf16
__global__ __launch_bounds__(256) void k_pwt(const void* __restrict__ w,
                                             u16* __restrict__ pwT,
                                             const int* __restrict__ flag) {
    int fl = *flag;
    int idx = blockIdx.x * 256 + threadIdx.x;   // 786432 total
    int c = idx % 768;
    int f = (idx / 768) & 255;
    int l = idx / (768 * 256);
    long long s = ((long long)l * 768 + c) * 256 + f;
    pwT[idx] = fl ? f2b(((const float*)w)[s]) : ((const u16*)w)[s];
}

// ---------------------------------------------------------------------------
// Head-weight transpose (1,256,3,3) -> wH[k][ic] bf16, and zero the 512B pad.
__global__ __launch_bounds__(256) void k_wh(const void* __restrict__ w,
                                            u16* __restrict__ wH,
                                            u16* __restrict__ zp,
                                            const int* __restrict__ flag) {
    int fl = *flag;
    int k = blockIdx.x;            // 0..8
    int ic = threadIdx.x;
    wH[k * 256 + ic] = fl ? f2b(((const float*)w)[ic * 9 + k])
                          : ((const u16*)w)[ic * 9 + k];
    if (blockIdx.x == 0) zp[ic] = 0;
}

// ---------------------------------------------------------------------------
// Fusion pass 1 (MFMA, BK=32): per (b,l) 128px x 128f GEMM over K=768,
// epilogue gelu * softmax(lw)[l] -> gbuf[(l,b)][px][f] f32 (channels-last).
// A staged via swizzled LDS (strided source); B direct per-lane 16B loads
// from pwT (L2-resident). MFMA operands swapped so f lands on the (quad,reg)
// axis -> vectorized float4 stores at [px][f].
__global__ __launch_bounds__(256) void k_fgemm(
    const void* __restrict__ f1, const void* __restrict__ f2,
    const void* __restrict__ f3, const void* __restrict__ f4,
    const u16* __restrict__ pwT, const void* __restrict__ lwp,
    const int* __restrict__ flag, float* __restrict__ gbuf)
{
    __shared__ u16 As[128 * 32];
    const int fl = *flag;
    const int t    = threadIdx.x;
    const int lane = t & 63;
    const int wv   = t >> 6;
    const int mbase = (wv & 1) << 6;
    const int nbase = (wv >> 1) << 6;
    const int quad  = lane >> 4;
    const int l15   = lane & 15;

    const int f0 = blockIdx.x << 7;
    const int m0 = blockIdx.y << 7;
    const int b  = blockIdx.z >> 2;
    const int l  = blockIdx.z & 3;
    const void* fp = (l == 0) ? f1 : (l == 1) ? f2 : (l == 2) ? f3 : f4;

    float w0 = ldx(lwp, 0, fl), w1 = ldx(lwp, 1, fl);
    float w2 = ldx(lwp, 2, fl), w3 = ldx(lwp, 3, fl);
    float mx = fmaxf(fmaxf(w0, w1), fmaxf(w2, w3));
    float e0 = expf(w0 - mx), e1 = expf(w1 - mx), e2 = expf(w2 - mx), e3 = expf(w3 - mx);
    float es = e0 + e1 + e2 + e3;
    float lwl = ((l == 0) ? e0 : (l == 1) ? e1 : (l == 2) ? e2 : e3) / es;

    const int spx = t & 127;      // px row staged
    const int sq  = t >> 7;       // which 16-k half

    const int sw  = (spx >> 1) & 3;
    const int aw0 = spx * 32 + (((sq << 1) ^ sw) << 3);
    const int aw1 = spx * 32 + ((((sq << 1) | 1) ^ sw) << 3);
    int ard[4];
    #pragma unroll
    for (int i = 0; i < 4; ++i) {
        int ra = mbase + (i << 4) + l15;
        ard[i] = ra * 32 + ((quad ^ ((ra >> 1) & 3)) << 3);
    }
    // B direct-load row offsets
    const u16* srcBb = pwT + (size_t)l * 196608 + (size_t)f0 * 768 + (quad << 3);
    int bofs[4];
    #pragma unroll
    for (int j = 0; j < 4; ++j)
        bofs[j] = (nbase + (j << 4) + l15) * 768;

    f32x4 acc[4][4];
    #pragma unroll
    for (int i = 0; i < 4; ++i)
        #pragma unroll
        for (int j = 0; j < 4; ++j) acc[i][j] = (f32x4)0.f;

    const size_t abase = (size_t)b * 768 * 1024 + m0 + spx;

    alignas(16) u16 av[16];
    float afv[16];
    auto issue = [&](int k0) {
        if (fl) {
            #pragma unroll
            for (int s = 0; s < 16; ++s)
                afv[s] = ((const float*)fp)[abase + (size_t)(k0 + sq * 16 + s) * 1024];
        } else {
            #pragma unroll
            for (int s = 0; s < 16; ++s)
                av[s] = ((const u16*)fp)[abase + (size_t)(k0 + sq * 16 + s) * 1024];
        }
    };

    issue(0);
    for (int k0 = 0; k0 < 768; k0 += 32) {
        __syncthreads();
        if (fl) {
            #pragma unroll
            for (int s = 0; s < 16; ++s) av[s] = f2b(afv[s]);
        }
        *(uint4*)&As[aw0] = *(const uint4*)&av[0];
        *(uint4*)&As[aw1] = *(const uint4*)&av[8];
        __syncthreads();
        if (k0 < 736) issue(k0 + 32);
        __builtin_amdgcn_sched_barrier(0);

        short8 af[4], bf[4];
        #pragma unroll
        for (int i = 0; i < 4; ++i) af[i] = *(const short8*)&As[ard[i]];
        #pragma unroll
        for (int j = 0; j < 4; ++j) bf[j] = *(const short8*)(srcBb + bofs[j] + k0);
        #pragma unroll
        for (int i = 0; i < 4; ++i)
            #pragma unroll
            for (int j = 0; j < 4; ++j)
                acc[i][j] = __builtin_amdgcn_mfma_f32_16x16x32_bf16(
                    bf[j], af[i], acc[i][j], 0, 0, 0);
    }

    // epilogue: gelu * lw[l]; channels-last store [px][f..f+3]
    #pragma unroll
    for (int j = 0; j < 4; ++j) {
        const int fb = f0 + nbase + (j << 4) + (quad << 2);
        #pragma unroll
        for (int i = 0; i < 4; ++i) {
            const int px = m0 + mbase + (i << 4) + l15;
            f32x4 a = acc[i][j];
            float4 o;
            o.x = lwl * 0.5f * a[0] * (1.f + erff(a[0] * 0.70710678118654752f));
            o.y = lwl * 0.5f * a[1] * (1.f + erff(a[1] * 0.70710678118654752f));
            o.z = lwl * 0.5f * a[2] * (1.f + erff(a[2] * 0.70710678118654752f));
            o.w = lwl * 0.5f * a[3] * (1.f + erff(a[3] * 0.70710678118654752f));
            *(float4*)(gbuf + ((size_t)((l << 2) + b) * 1024 + px) * 256 + fb) = o;
        }
    }
}

// Fusion pass 2: x0 = sum over 4 layer slabs (layout-agnostic).
__global__ __launch_bounds__(256) void k_fsum(const float* __restrict__ gbuf,
                                              float* __restrict__ x0)
{
    int idx = blockIdx.x * 256 + threadIdx.x;   // 1048576 total
    x0[idx] = gbuf[idx] + gbuf[1048576 + idx]
            + gbuf[2097152 + idx] + gbuf[3145728 + idx];
}

// ---------------------------------------------------------------------------
// Depthwise 3x3 + BN + residual ReLU, channels-last (4,1024px,256) f32 -> f32
__global__ __launch_bounds__(256) void k_dw(const float* __restrict__ x0,
                                            const void* __restrict__ dww,
                                            const void* __restrict__ bnp,
                                            const int* __restrict__ flag,
                                            float* __restrict__ x1)
{
    const int fl = *flag;
    int idx = blockIdx.x * 256 + threadIdx.x;     // 1048576 total
    int f   = idx & 255;
    int bpx = idx >> 8;
    int n   = bpx & 1023;
    int bb  = bpx >> 10;
    int h = n >> 5, w = n & 31;
    const float* xb = x0 + ((size_t)(bb << 10)) * 256;
    float acc = 0.f;
    #pragma unroll
    for (int kh = 0; kh < 3; ++kh) {
        int y = h + kh - 1;
        if (y < 0 || y >= 32) continue;
        #pragma unroll
        for (int kw = 0; kw < 3; ++kw) {
            int x = w + kw - 1;
            if (x < 0 || x >= 32) continue;
            acc += xb[(size_t)((y << 5) + x) * 256 + f]
                 * ldx(dww, f * 9 + kh * 3 + kw, fl);
        }
    }
    float g  = ldx(bnp, f, fl);
    float be = ldx(bnp, 256 + f, fl);
    float mn = ldx(bnp, 512 + f, fl);
    float vv = ldx(bnp, 768 + f, fl);
    float scale = g / sqrtf(vv + 1e-5f);
    float o = (acc - mn) * scale + be + x0[idx];
    x1[idx] = fmaxf(o, 0.f);
}

// ---------------------------------------------------------------------------
// 1x1 offset conv, channels-last act (B,HW,256) -> off (B,32,HW) f32.
template<bool ACT_BF16>
__global__ __launch_bounds__(256) void k_offs(const void* __restrict__ actv,
                                              const void* __restrict__ w,
                                              const void* __restrict__ bias,
                                              const int* __restrict__ flag,
                                              float* __restrict__ off,
                                              int HW)
{
    const int fl = *flag;
    int idx = blockIdx.x * 256 + threadIdx.x;     // B*32*HW total
    int pos = idx % HW;
    int oc  = (idx / HW) & 31;
    int b   = idx / (32 * HW);
    float acc = 0.f;
    if (ACT_BF16) {
        const u16* ap = (const u16*)actv + ((size_t)b * HW + pos) * 256;
        #pragma unroll 4
        for (int icc = 0; icc < 32; ++icc) {
            short8 v = *(const short8*)(ap + icc * 8);
            #pragma unroll
            for (int s = 0; s < 8; ++s)
                acc = fmaf(b2f((u16)v[s]), ldx(w, oc * 256 + icc * 8 + s, fl), acc);
        }
    } else {
        const float* ap = (const float*)actv + ((size_t)b * HW + pos) * 256;
        #pragma unroll 4
        for (int icc = 0; icc < 32; ++icc) {
            f32x4 v0 = *(const f32x4*)(ap + icc * 8);
            f32x4 v1 = *(const f32x4*)(ap + icc * 8 + 4);
            #pragma unroll
            for (int s = 0; s < 4; ++s) {
                acc = fmaf(v0[s], ldx(w, oc * 256 + icc * 8 + s, fl), acc);
                acc = fmaf(v1[s], ldx(w, oc * 256 + icc * 8 + 4 + s, fl), acc);
            }
        }
    }
    off[idx] = acc + ldx(bias, oc, fl);
}

// ---------------------------------------------------------------------------
// DySample grid sample x2, channels-last in/out. Thread -> (b, ho, wo, c);
// c = idx&255 gives coalesced gathers and contiguous stores.
template<bool ACT_BF16>
__global__ __launch_bounds__(256) void k_sample(const void* __restrict__ actv,
                                                const float* __restrict__ off,
                                                u16* __restrict__ out,
                                                int H, int W, int logWo)
{
    const int Wo = W << 1, Ho = H << 1;
    const int HW = H * W;
    int idx = blockIdx.x * 256 + threadIdx.x;
    int c  = idx & 255;
    int q  = idx >> 8;
    int wo = q & (Wo - 1);
    int ho = (q >> logWo) & (Ho - 1);
    int b  = q >> (logWo << 1);            // square: logHo == logWo
    int g  = c >> 6;
    int h = ho >> 1, a = ho & 1, w = wo >> 1, bb = wo & 1;
    int och = g * 4 + a * 2 + bb;
    size_t obase = ((size_t)b * 32 + och) * HW + h * W + w;
    float offx = off[obase];
    float offy = off[obase + (size_t)16 * HW];
    float xp = (float)w + (bb ? 0.25f : -0.25f) + 0.25f * offx;
    float yp = (float)h + (a  ? 0.25f : -0.25f) + 0.25f * offy;
    xp = fminf(fmaxf(xp, 0.f), (float)(W - 1));
    yp = fminf(fmaxf(yp, 0.f), (float)(H - 1));
    float xf = floorf(xp), yf = floorf(yp);
    float wx = xp - xf, wy = yp - yf;
    int x0i = (int)xf; x0i = max(0, min(x0i, W - 1));
    int y0i = (int)yf; y0i = max(0, min(y0i, H - 1));
    int x1i = min(x0i + 1, W - 1);
    int y1i = min(y0i + 1, H - 1);
    float v00, v01, v10, v11;
    if (ACT_BF16) {
        const u16* ap = (const u16*)actv + (size_t)b * HW * 256;
        v00 = b2f(ap[(size_t)(y0i * W + x0i) * 256 + c]);
        v01 = b2f(ap[(size_t)(y0i * W + x1i) * 256 + c]);
        v10 = b2f(ap[(size_t)(y1i * W + x0i) * 256 + c]);
        v11 = b2f(ap[(size_t)(y1i * W + x1i) * 256 + c]);
    } else {
        const float* ap = (const float*)actv + (size_t)b * HW * 256;
        v00 = ap[(size_t)(y0i * W + x0i) * 256 + c];
        v01 = ap[(size_t)(y0i * W + x1i) * 256 + c];
        v10 = ap[(size_t)(y1i * W + x0i) * 256 + c];
        v11 = ap[(size_t)(y1i * W + x1i) * 256 + c];
    }
    float r = v00 * (1.f - wy) * (1.f - wx) + v01 * (1.f - wy) * wx
            + v10 * wy * (1.f - wx) + v11 * wy * wx;
    out[idx] = f2b(r);
}

// ---------------------------------------------------------------------------
// Barrier-free MFMA implicit-GEMM 3x3 conv 256->256 + BN + ReLU,
// channels-last bf16 in/out [px][ch]. No LDS: A and B fragments are direct
// per-lane 16B global loads (a wave's fragment = 16 fully-used cache lines).
// MFMA operands swapped -> oc on (quad,reg) axis -> ushort4 stores [px][oc].
// OOB taps: pointer-select into a 512B zero pad (1 cndmask per row per tap).
// Block = 128 px x 64 oc, 4 waves (wave 64px x 32oc, acc[4][2]).
// grid: (4 oc-quarters, HW/128, nb).
template<int LOGW>
__global__ __launch_bounds__(256) void k_cnl(const u16* __restrict__ in,
                                             const u16* __restrict__ wTo,
                                             const void* __restrict__ bnp,
                                             const int* __restrict__ flag,
                                             const u16* __restrict__ zp,
                                             u16* __restrict__ out,
                                             int H)
{
    constexpr int W = 1 << LOGW;
    const int fl = *flag;
    const int HW = H * W;
    const int t    = threadIdx.x;
    const int lane = t & 63;
    const int wv   = t >> 6;
    const int mhalf = (wv & 1) << 6;     // px half within 128-tile
    const int nq    = (wv >> 1) << 5;    // oc sub within 64-tile
    const int quad  = lane >> 4;
    const int l15   = lane & 15;

    const int oc0 = blockIdx.x << 6;
    const int px0 = blockIdx.y << 7;
    const u16* inb  = in  + (size_t)blockIdx.z * 256 * HW;
    u16*       outb = out + (size_t)blockIdx.z * 256 * HW;

    const int pxw = px0 + mhalf;         // multiple of 64 -> one image row/wave
    const int gy  = pxw >> LOGW;         // wave-uniform row
    const int gxb = pxw & (W - 1);

    const u16* inq = inb + (quad << 3);
    const u16* wb  = wTo + (oc0 << 8) + (quad << 3);
    const int zofs = (int)(zp - inb);    // offset of zero pad (element units)

    f32x4 acc[4][2];
    #pragma unroll
    for (int i = 0; i < 4; ++i)
        #pragma unroll
        for (int j = 0; j < 2; ++j) acc[i][j] = (f32x4)0.f;

    for (int dh = 0; dh < 3; ++dh) {
        const int ys = gy + dh - 1;
        const bool yok = (unsigned)ys < (unsigned)H;
        const int ybase = ys * W;
        for (int dwt = 0; dwt < 3; ++dwt) {
            const int tofs = (dh * 3 + dwt) << 16;       // tap * 65536
            int aofs[4];
            #pragma unroll
            for (int i = 0; i < 4; ++i) {
                int xs = gxb + (i << 4) + l15 + dwt - 1;
                bool ok = yok && ((unsigned)xs < (unsigned)W);
                aofs[i] = ok ? ((ybase + xs) << 8) : zofs;
            }
            const u16* wt = wb + tofs + (nq << 8);
            #pragma unroll
            for (int icc = 0; icc < 8; ++icc) {
                short8 bf0 = *(const short8*)(wt + (l15 << 8) + (icc << 5));
                short8 bf1 = *(const short8*)(wt + ((16 + l15) << 8) + (icc << 5));
                short8 af0 = *(const short8*)(inq + aofs[0] + (icc << 5));
                short8 af1 = *(const short8*)(inq + aofs[1] + (icc << 5));
                short8 af2 = *(const short8*)(inq + aofs[2] + (icc << 5));
                short8 af3 = *(const short8*)(inq + aofs[3] + (icc << 5));
                acc[0][0] = __builtin_amdgcn_mfma_f32_16x16x32_bf16(bf0, af0, acc[0][0], 0, 0, 0);
                acc[0][1] = __builtin_amdgcn_mfma_f32_16x16x32_bf16(bf1, af0, acc[0][1], 0, 0, 0);
                acc[1][0] = __builtin_amdgcn_mfma_f32_16x16x32_bf16(bf0, af1, acc[1][0], 0, 0, 0);
                acc[1][1] = __builtin_amdgcn_mfma_f32_16x16x32_bf16(bf1, af1, acc[1][1], 0, 0, 0);
                acc[2][0] = __builtin_amdgcn_mfma_f32_16x16x32_bf16(bf0, af2, acc[2][0], 0, 0, 0);
                acc[2][1] = __builtin_amdgcn_mfma_f32_16x16x32_bf16(bf1, af2, acc[2][1], 0, 0, 0);
                acc[3][0] = __builtin_amdgcn_mfma_f32_16x16x32_bf16(bf0, af3, acc[3][0], 0, 0, 0);
                acc[3][1] = __builtin_amdgcn_mfma_f32_16x16x32_bf16(bf1, af3, acc[3][1], 0, 0, 0);
            }
        }
    }

    #pragma unroll
    for (int j = 0; j < 2; ++j) {
        const int f = oc0 + nq + (j << 4) + (quad << 2);
        float sc[4], sh[4];
        #pragma unroll
        for (int r = 0; r < 4; ++r) {
            float g  = ldx(bnp, f + r, fl);
            float be = ldx(bnp, 256 + f + r, fl);
            float mn = ldx(bnp, 512 + f + r, fl);
            float vv = ldx(bnp, 768 + f + r, fl);
            sc[r] = g / sqrtf(vv + 1e-5f);
            sh[r] = be - mn * sc[r];
        }
        #pragma unroll
        for (int i = 0; i < 4; ++i) {
            const int px = px0 + mhalf + (i << 4) + l15;
            f32x4 a = acc[i][j];
            ushort4 o;
            o.x = f2b(fmaxf(a[0] * sc[0] + sh[0], 0.f));
            o.y = f2b(fmaxf(a[1] * sc[1] + sh[1], 0.f));
            o.z = f2b(fmaxf(a[2] * sc[2] + sh[2], 0.f));
            o.w = f2b(fmaxf(a[3] * sc[3] + sh[3], 0.f));
            *(ushort4*)(outb + (size_t)px * 256 + f) = o;
        }
    }
}

// ---------------------------------------------------------------------------
// Head: 3x3 conv 256->1, channels-last input, one thread per output px.
__global__ __launch_bounds__(256) void k_head(const u16* __restrict__ in,
                                              const u16* __restrict__ wH,
                                              const void* __restrict__ bias,
                                              const int* __restrict__ flag,
                                              void* __restrict__ outp,
                                              int b0)
{
    const int fl = *flag;
    const int px = blockIdx.x * 256 + threadIdx.x;    // 0..16383
    const u16* inb = in + (size_t)blockIdx.y * 16384 * 256;
    const int x = px & 127, y = px >> 7;
    float acc = ldx(bias, 0, fl);
    #pragma unroll
    for (int kh = 0; kh < 3; ++kh) {
        int yy = y + kh - 1;
        if (yy < 0 || yy >= 128) continue;
        #pragma unroll
        for (int kw = 0; kw < 3; ++kw) {
            int xx = x + kw - 1;
            if (xx < 0 || xx >= 128) continue;
            const u16* p  = inb + (size_t)((yy << 7) + xx) * 256;
            const u16* wp = wH + (kh * 3 + kw) * 256;
            #pragma unroll 4
            for (int icc = 0; icc < 32; ++icc) {
                short8 v = *(const short8*)(p + icc * 8);
                short8 wv8 = *(const short8*)(wp + icc * 8);
                #pragma unroll
                for (int s = 0; s < 8; ++s)
                    acc = fmaf(b2f((u16)v[s]), b2f((u16)wv8[s]), acc);
            }
        }
    }
    int out_ofs = (b0 + blockIdx.y) * 16384 + px;
    if (fl) ((float*)outp)[out_ofs] = acc;
    else    ((u16*)outp)[out_ofs] = f2b(acc);
}

// ---------------------------------------------------------------------------
extern "C" void kernel_launch(void* const* d_in, const int* in_sizes, int n_in,
                              void* d_out, int out_size, void* d_ws, size_t ws_size,
                              hipStream_t stream) {
    (void)in_sizes; (void)n_in; (void)out_size;
    const void* f1     = d_in[0];
    const void* f2     = d_in[1];
    const void* f3     = d_in[2];
    const void* f4     = d_in[3];
    const void* proj_w = d_in[4];
    const void* lwp    = d_in[5];
    const void* dw_w   = d_in[6];
    const void* bn_enh = d_in[7];
    const void* ow1    = d_in[8];
    const void* ob1    = d_in[9];
    const void* cw1    = d_in[10];
    const void* bn1    = d_in[11];
    const void* ow2    = d_in[12];
    const void* ob2    = d_in[13];
    const void* cw2    = d_in[14];
    const void* bn2    = d_in[15];
    const void* out_w  = d_in[16];
    const void* out_b  = d_in[17];

    // stage-2 chunking by available workspace (ws_size is host-visible)
    const int nb = (ws_size >= 81592320ull) ? 4
                 : (ws_size >= 48037888ull) ? 2 : 1;

    // ---- workspace layout (all buffers same sizes as before; layouts are
    //      permutations to channels-last). wH/zp live in the flag gap. ----
    char* ws = (char*)d_ws;
    int*   flag = (int*)  (ws + 0);
    u16*   wH   = (u16*)  (ws + 4096);        // 4608 B head weights
    u16*   zp   = (u16*)  (ws + 16384);       // 512 B zero pad
    u16*   wT1  = (u16*)  (ws + 65536);
    u16*   wT2  = (u16*)  (ws + 1245184);
    u16*   pwT  = (u16*)  (ws + 2424832);
    u16*   c1   = (u16*)  (ws + 3997696);     // 8 MB bf16 (4, 4096px, 256)
    float* o2   = (float*)(ws + 12386304);    // 2 MB f32 (4,32,64,64)
    u16*   up2c = (u16*)  (ws + 14483456);    // nb*8 MB bf16 (nb,16384px,256)
    u16*   c2c  = (u16*)  (ws + 14483456 + (size_t)nb * 8388608);  // nb*8 MB
    float* gbuf = (float*)(ws + 3997696);     // 16 MB, dead before c1/o2/up1
    float* x0   = (float*)(ws + 20774912);    // 4 MB (dead before up2c/c2c)
    float* x1   = (float*)(ws + 24969216);    // 4 MB
    float* o1   = (float*)(ws + 29163520);    // 0.5 MB
    u16*   up1  = (u16*)  (ws + 12386304);    // 8 MB, overlaps o2 (dead then)

    // 0) dtype detect + weight transposes
    k_detect<<<1, 256, 0, stream>>>(f1, flag);
    k_wt<<<2304, 256, 0, stream>>>(cw1, wT1, flag);
    k_wt<<<2304, 256, 0, stream>>>(cw2, wT2, flag);
    k_pwt<<<3072, 256, 0, stream>>>(proj_w, pwT, flag);
    k_wh<<<9, 256, 0, stream>>>(out_w, wH, zp, flag);

    // 1) weighted fusion (MFMA) -> gbuf, then sum -> x0 (channels-last)
    k_fgemm<<<dim3(2, 8, 16), 256, 0, stream>>>(f1, f2, f3, f4, pwT, lwp, flag, gbuf);
    k_fsum<<<4096, 256, 0, stream>>>(gbuf, x0);

    // 2) spatial detail enhancer -> x1 f32 (channels-last)
    k_dw<<<4096, 256, 0, stream>>>(x0, dw_w, bn_enh, flag, x1);

    // 3) dysample #1 (32->64) + conv1 -> c1 bf16 (all 4 batches)
    k_offs<false><<<512, 256, 0, stream>>>(x1, ow1, ob1, flag, o1, 32 * 32);
    k_sample<false><<<16384, 256, 0, stream>>>(x1, o1, up1, 32, 32, 6);
    k_cnl<6><<<dim3(4, 32, 4), 256, 0, stream>>>(up1, wT1, bn1, flag, zp, c1, 64);

    // 4) offsets for stage 2 (all batches)
    k_offs<true><<<2048, 256, 0, stream>>>(c1, ow2, ob2, flag, o2, 64 * 64);

    // 5) chunked: dysample #2 (64->128) + conv2 + head
    for (int b0 = 0; b0 < 4; b0 += nb) {
        const u16*   c1b = c1 + (size_t)b0 * 4096 * 256;
        const float* o2b = o2 + (size_t)b0 * 32 * 4096;
        k_sample<true><<<16384 * nb, 256, 0, stream>>>(c1b, o2b, up2c, 64, 64, 7);
        k_cnl<7><<<dim3(4, 128, nb), 256, 0, stream>>>(up2c, wT2, bn2, flag, zp,
                                                       c2c, 128);
        k_head<<<dim3(64, nb), 256, 0, stream>>>(c2c, wH, out_b, flag, d_out, b0);
    }
}

// Round 6
// 705.239 us; speedup vs baseline: 1.2221x; 1.2221x over previous
//
#include <hip/hip_runtime.h>
#include <math.h>

using u16 = unsigned short;
typedef __attribute__((ext_vector_type(8))) short short8;
typedef __attribute__((ext_vector_type(4))) float f32x4;

__device__ __forceinline__ float b2f(u16 u) {
    union { unsigned int i; float f; } v; v.i = ((unsigned int)u) << 16; return v.f;
}
__device__ __forceinline__ u16 f2b(float f) {
    union { float f; unsigned int i; } v; v.f = f;
    unsigned int x = v.i;
    return (u16)((x + 0x7FFFu + ((x >> 16) & 1u)) >> 16);
}
// dtype-adaptive external load: fl=1 -> f32, fl=0 -> bf16
__device__ __forceinline__ float ldx(const void* p, long long i, int fl) {
    return fl ? ((const float*)p)[i] : b2f(((const u16*)p)[i]);
}

// ---------------------------------------------------------------------------
// Detect input dtype: read first 4096 u16 of f1 as bf16. flag=1 means f32.
__global__ __launch_bounds__(256) void k_detect(const void* p, int* flag) {
    __shared__ float m[256];
    int t = threadIdx.x;
    const u16* q = (const u16*)p;
    float lm = 0.f;
    for (int j = 0; j < 16; ++j) {
        float v = b2f(q[t * 16 + j]);
        float a = fabsf(v);
        if (!(a <= 1e30f)) a = 1e31f;   // NaN/Inf -> huge
        lm = fmaxf(lm, a);
    }
    m[t] = lm;
    __syncthreads();
    if (t == 0) {
        float mm = 0.f;
        for (int i = 0; i < 256; ++i) mm = fmaxf(mm, m[i]);
        *flag = (mm > 1000.f) ? 1 : 0;
    }
}

// ---------------------------------------------------------------------------
// Weight transpose: conv w (OC=256, IC=256, 3, 3) -> wTo[9][OC][IC] bf16
__global__ __launch_bounds__(256) void k_wt(const void* __restrict__ w,
                                            u16* __restrict__ wTo,
                                            const int* __restrict__ flag) {
    int fl = *flag;
    int idx = blockIdx.x * 256 + threadIdx.x;
    int k  = idx >> 16;          // 0..8
    int oc = (idx >> 8) & 255;
    int ic = idx & 255;
    long long s = (oc * 256 + ic) * 9 + k;
    wTo[idx] = fl ? f2b(((const float*)w)[s]) : ((const u16*)w)[s];
}

// ---------------------------------------------------------------------------
// proj_w transpose: (L=4, C=768, F=256) -> pwT[l][f][c] bf16
__global__ __launch_bounds__(256) void k_pwt(const void* __restrict__ w,
                                             u16* __restrict__ pwT,
                                             const int* __restrict__ flag) {
    int fl = *flag;
    int idx = blockIdx.x * 256 + threadIdx.x;   // 786432 total
    int c = idx % 768;
    int f = (idx / 768) & 255;
    int l = idx / (768 * 256);
    long long s = ((long long)l * 768 + c) * 256 + f;
    pwT[idx] = fl ? f2b(((const float*)w)[s]) : ((const u16*)w)[s];
}

// ---------------------------------------------------------------------------
// Head-weight transpose (1,256,3,3) -> wH[k][ic] bf16.
__global__ __launch_bounds__(256) void k_wh(const void* __restrict__ w,
                                            u16* __restrict__ wH,
                                            const int* __restrict__ flag) {
    int fl = *flag;
    int k = blockIdx.x;            // 0..8
    int ic = threadIdx.x;
    wH[k * 256 + ic] = fl ? f2b(((const float*)w)[ic * 9 + k])
                          : ((const u16*)w)[ic * 9 + k];
}

// ---------------------------------------------------------------------------
// Fusion pass 1 (MFMA, BK=32): per (b,l) 128px x 128f GEMM over K=768,
// epilogue gelu * softmax(lw)[l] -> gbuf[(l,b)][px][f] f32 (channels-last).
// A staged via swizzled LDS (strided source); B direct per-lane 16B loads
// from pwT (L2-resident). MFMA operands swapped so f lands on the (quad,reg)
// axis -> vectorized float4 stores at [px][f].
__global__ __launch_bounds__(256) void k_fgemm(
    const void* __restrict__ f1, const void* __restrict__ f2,
    const void* __restrict__ f3, const void* __restrict__ f4,
    const u16* __restrict__ pwT, const void* __restrict__ lwp,
    const int* __restrict__ flag, float* __restrict__ gbuf)
{
    __shared__ u16 As[128 * 32];
    const int fl = *flag;
    const int t    = threadIdx.x;
    const int lane = t & 63;
    const int wv   = t >> 6;
    const int mbase = (wv & 1) << 6;
    const int nbase = (wv >> 1) << 6;
    const int quad  = lane >> 4;
    const int l15   = lane & 15;

    const int f0 = blockIdx.x << 7;
    const int m0 = blockIdx.y << 7;
    const int b  = blockIdx.z >> 2;
    const int l  = blockIdx.z & 3;
    const void* fp = (l == 0) ? f1 : (l == 1) ? f2 : (l == 2) ? f3 : f4;

    float w0 = ldx(lwp, 0, fl), w1 = ldx(lwp, 1, fl);
    float w2 = ldx(lwp, 2, fl), w3 = ldx(lwp, 3, fl);
    float mx = fmaxf(fmaxf(w0, w1), fmaxf(w2, w3));
    float e0 = expf(w0 - mx), e1 = expf(w1 - mx), e2 = expf(w2 - mx), e3 = expf(w3 - mx);
    float es = e0 + e1 + e2 + e3;
    float lwl = ((l == 0) ? e0 : (l == 1) ? e1 : (l == 2) ? e2 : e3) / es;

    const int spx = t & 127;      // px row staged
    const int sq  = t >> 7;       // which 16-k half

    const int sw  = (spx >> 1) & 3;
    const int aw0 = spx * 32 + (((sq << 1) ^ sw) << 3);
    const int aw1 = spx * 32 + ((((sq << 1) | 1) ^ sw) << 3);
    int ard[4];
    #pragma unroll
    for (int i = 0; i < 4; ++i) {
        int ra = mbase + (i << 4) + l15;
        ard[i] = ra * 32 + ((quad ^ ((ra >> 1) & 3)) << 3);
    }
    // B direct-load row offsets
    const u16* srcBb = pwT + (size_t)l * 196608 + (size_t)f0 * 768 + (quad << 3);
    int bofs[4];
    #pragma unroll
    for (int j = 0; j < 4; ++j)
        bofs[j] = (nbase + (j << 4) + l15) * 768;

    f32x4 acc[4][4];
    #pragma unroll
    for (int i = 0; i < 4; ++i)
        #pragma unroll
        for (int j = 0; j < 4; ++j) acc[i][j] = (f32x4)0.f;

    const size_t abase = (size_t)b * 768 * 1024 + m0 + spx;

    alignas(16) u16 av[16];
    float afv[16];
    auto issue = [&](int k0) {
        if (fl) {
            #pragma unroll
            for (int s = 0; s < 16; ++s)
                afv[s] = ((const float*)fp)[abase + (size_t)(k0 + sq * 16 + s) * 1024];
        } else {
            #pragma unroll
            for (int s = 0; s < 16; ++s)
                av[s] = ((const u16*)fp)[abase + (size_t)(k0 + sq * 16 + s) * 1024];
        }
    };

    issue(0);
    for (int k0 = 0; k0 < 768; k0 += 32) {
        __syncthreads();
        if (fl) {
            #pragma unroll
            for (int s = 0; s < 16; ++s) av[s] = f2b(afv[s]);
        }
        *(uint4*)&As[aw0] = *(const uint4*)&av[0];
        *(uint4*)&As[aw1] = *(const uint4*)&av[8];
        __syncthreads();
        if (k0 < 736) issue(k0 + 32);
        __builtin_amdgcn_sched_barrier(0);

        short8 af[4], bf[4];
        #pragma unroll
        for (int i = 0; i < 4; ++i) af[i] = *(const short8*)&As[ard[i]];
        #pragma unroll
        for (int j = 0; j < 4; ++j) bf[j] = *(const short8*)(srcBb + bofs[j] + k0);
        #pragma unroll
        for (int i = 0; i < 4; ++i)
            #pragma unroll
            for (int j = 0; j < 4; ++j)
                acc[i][j] = __builtin_amdgcn_mfma_f32_16x16x32_bf16(
                    bf[j], af[i], acc[i][j], 0, 0, 0);
    }

    // epilogue: gelu * lw[l]; channels-last store [px][f..f+3]
    #pragma unroll
    for (int j = 0; j < 4; ++j) {
        const int fb = f0 + nbase + (j << 4) + (quad << 2);
        #pragma unroll
        for (int i = 0; i < 4; ++i) {
            const int px = m0 + mbase + (i << 4) + l15;
            f32x4 a = acc[i][j];
            float4 o;
            o.x = lwl * 0.5f * a[0] * (1.f + erff(a[0] * 0.70710678118654752f));
            o.y = lwl * 0.5f * a[1] * (1.f + erff(a[1] * 0.70710678118654752f));
            o.z = lwl * 0.5f * a[2] * (1.f + erff(a[2] * 0.70710678118654752f));
            o.w = lwl * 0.5f * a[3] * (1.f + erff(a[3] * 0.70710678118654752f));
            *(float4*)(gbuf + ((size_t)((l << 2) + b) * 1024 + px) * 256 + fb) = o;
        }
    }
}

// Fusion pass 2: x0 = sum over 4 layer slabs (layout-agnostic).
__global__ __launch_bounds__(256) void k_fsum(const float* __restrict__ gbuf,
                                              float* __restrict__ x0)
{
    int idx = blockIdx.x * 256 + threadIdx.x;   // 1048576 total
    x0[idx] = gbuf[idx] + gbuf[1048576 + idx]
            + gbuf[2097152 + idx] + gbuf[3145728 + idx];
}

// ---------------------------------------------------------------------------
// Depthwise 3x3 + BN + residual ReLU, channels-last (4,1024px,256) f32 -> f32
__global__ __launch_bounds__(256) void k_dw(const float* __restrict__ x0,
                                            const void* __restrict__ dww,
                                            const void* __restrict__ bnp,
                                            const int* __restrict__ flag,
                                            float* __restrict__ x1)
{
    const int fl = *flag;
    int idx = blockIdx.x * 256 + threadIdx.x;     // 1048576 total
    int f   = idx & 255;
    int bpx = idx >> 8;
    int n   = bpx & 1023;
    int bb  = bpx >> 10;
    int h = n >> 5, w = n & 31;
    const float* xb = x0 + ((size_t)(bb << 10)) * 256;
    float acc = 0.f;
    #pragma unroll
    for (int kh = 0; kh < 3; ++kh) {
        int y = h + kh - 1;
        if (y < 0 || y >= 32) continue;
        #pragma unroll
        for (int kw = 0; kw < 3; ++kw) {
            int x = w + kw - 1;
            if (x < 0 || x >= 32) continue;
            acc += xb[(size_t)((y << 5) + x) * 256 + f]
                 * ldx(dww, f * 9 + kh * 3 + kw, fl);
        }
    }
    float g  = ldx(bnp, f, fl);
    float be = ldx(bnp, 256 + f, fl);
    float mn = ldx(bnp, 512 + f, fl);
    float vv = ldx(bnp, 768 + f, fl);
    float scale = g / sqrtf(vv + 1e-5f);
    float o = (acc - mn) * scale + be + x0[idx];
    x1[idx] = fmaxf(o, 0.f);
}

// ---------------------------------------------------------------------------
// 1x1 offset conv, channels-last act (B,HW,256) -> off (B,32,HW) f32.
template<bool ACT_BF16>
__global__ __launch_bounds__(256) void k_offs(const void* __restrict__ actv,
                                              const void* __restrict__ w,
                                              const void* __restrict__ bias,
                                              const int* __restrict__ flag,
                                              float* __restrict__ off,
                                              int HW)
{
    const int fl = *flag;
    int idx = blockIdx.x * 256 + threadIdx.x;     // B*32*HW total
    int pos = idx % HW;
    int oc  = (idx / HW) & 31;
    int b   = idx / (32 * HW);
    float acc = 0.f;
    if (ACT_BF16) {
        const u16* ap = (const u16*)actv + ((size_t)b * HW + pos) * 256;
        #pragma unroll 4
        for (int icc = 0; icc < 32; ++icc) {
            short8 v = *(const short8*)(ap + icc * 8);
            #pragma unroll
            for (int s = 0; s < 8; ++s)
                acc = fmaf(b2f((u16)v[s]), ldx(w, oc * 256 + icc * 8 + s, fl), acc);
        }
    } else {
        const float* ap = (const float*)actv + ((size_t)b * HW + pos) * 256;
        #pragma unroll 4
        for (int icc = 0; icc < 32; ++icc) {
            f32x4 v0 = *(const f32x4*)(ap + icc * 8);
            f32x4 v1 = *(const f32x4*)(ap + icc * 8 + 4);
            #pragma unroll
            for (int s = 0; s < 4; ++s) {
                acc = fmaf(v0[s], ldx(w, oc * 256 + icc * 8 + s, fl), acc);
                acc = fmaf(v1[s], ldx(w, oc * 256 + icc * 8 + 4 + s, fl), acc);
            }
        }
    }
    off[idx] = acc + ldx(bias, oc, fl);
}

// ---------------------------------------------------------------------------
// DySample grid sample x2, channels-last in/out. Thread -> (b, ho, wo, c);
// c = idx&255 gives coalesced gathers and contiguous stores.
template<bool ACT_BF16>
__global__ __launch_bounds__(256) void k_sample(const void* __restrict__ actv,
                                                const float* __restrict__ off,
                                                u16* __restrict__ out,
                                                int H, int W, int logWo)
{
    const int Wo = W << 1, Ho = H << 1;
    const int HW = H * W;
    int idx = blockIdx.x * 256 + threadIdx.x;
    int c  = idx & 255;
    int q  = idx >> 8;
    int wo = q & (Wo - 1);
    int ho = (q >> logWo) & (Ho - 1);
    int b  = q >> (logWo << 1);            // square: logHo == logWo
    int g  = c >> 6;
    int h = ho >> 1, a = ho & 1, w = wo >> 1, bb = wo & 1;
    int och = g * 4 + a * 2 + bb;
    size_t obase = ((size_t)b * 32 + och) * HW + h * W + w;
    float offx = off[obase];
    float offy = off[obase + (size_t)16 * HW];
    float xp = (float)w + (bb ? 0.25f : -0.25f) + 0.25f * offx;
    float yp = (float)h + (a  ? 0.25f : -0.25f) + 0.25f * offy;
    xp = fminf(fmaxf(xp, 0.f), (float)(W - 1));
    yp = fminf(fmaxf(yp, 0.f), (float)(H - 1));
    float xf = floorf(xp), yf = floorf(yp);
    float wx = xp - xf, wy = yp - yf;
    int x0i = (int)xf; x0i = max(0, min(x0i, W - 1));
    int y0i = (int)yf; y0i = max(0, min(y0i, H - 1));
    int x1i = min(x0i + 1, W - 1);
    int y1i = min(y0i + 1, H - 1);
    float v00, v01, v10, v11;
    if (ACT_BF16) {
        const u16* ap = (const u16*)actv + (size_t)b * HW * 256;
        v00 = b2f(ap[(size_t)(y0i * W + x0i) * 256 + c]);
        v01 = b2f(ap[(size_t)(y0i * W + x1i) * 256 + c]);
        v10 = b2f(ap[(size_t)(y1i * W + x0i) * 256 + c]);
        v11 = b2f(ap[(size_t)(y1i * W + x1i) * 256 + c]);
    } else {
        const float* ap = (const float*)actv + (size_t)b * HW * 256;
        v00 = ap[(size_t)(y0i * W + x0i) * 256 + c];
        v01 = ap[(size_t)(y0i * W + x1i) * 256 + c];
        v10 = ap[(size_t)(y1i * W + x0i) * 256 + c];
        v11 = ap[(size_t)(y1i * W + x1i) * 256 + c];
    }
    float r = v00 * (1.f - wy) * (1.f - wx) + v01 * (1.f - wy) * wx
            + v10 * wy * (1.f - wx) + v11 * wy * wx;
    out[idx] = f2b(r);
}

// ---------------------------------------------------------------------------
// MFMA implicit-GEMM 3x3 conv 256->256 + BN + ReLU, channels-last bf16 in/out.
// r6 = r0's proven LDS-staged 128px x 128oc 2-barrier structure, but with:
//  - channels-last A: per-thread stage = 2 contiguous uint4 loads (was 16
//    strided 2B scalars -- the dominant r0/r2 latency+issue cost),
//  - pinned 1-deep prefetch (sched_barrier(0)),
//  - swapped-operand MFMA (verified r5): oc on (quad,reg) -> channels-last
//    ushort4 stores; i-outer store order = full-line write coalescing,
//  - bijective chunked XCD swizzle: oc-halves + neighbor px-tiles of one
//    image stay on one XCD -> A rows shared in that XCD's L2 (r5: 612MB
//    FETCH was exactly the no-reuse tap refetch).
// grid: (2 oc-halves, HW/128 px-tiles, batches); nwg % 8 == 0 always.
template<int LOGW>
__global__ __launch_bounds__(256) void k_cm5(const u16* __restrict__ in,
                                             const u16* __restrict__ wTo,
                                             const void* __restrict__ bnp,
                                             const int* __restrict__ flag,
                                             u16* __restrict__ out,
                                             int H)
{
    constexpr int W = 1 << LOGW;
    __shared__ u16 As[128 * 32];   // [px][32 ic], chunk-XOR swizzled
    __shared__ u16 Bs[128 * 32];   // [oc][32 ic]
    const int fl = *flag;
    const int HW = H * W;

    // chunked XCD swizzle (bijective; nwg multiple of 8)
    const unsigned nwg  = gridDim.x * gridDim.y * gridDim.z;
    const unsigned flat = (blockIdx.z * gridDim.y + blockIdx.y) * gridDim.x
                        + blockIdx.x;
    const unsigned wid  = (flat & 7u) * (nwg >> 3) + (flat >> 3);
    const int bx = wid & 1;                        // gridDim.x == 2
    const unsigned rem = wid >> 1;
    const int lgy = __ffs((int)gridDim.y) - 1;     // gridDim.y is pow2
    const int by = rem & (gridDim.y - 1);
    const int bz = rem >> lgy;

    const int t    = threadIdx.x;
    const int lane = t & 63;
    const int wv   = t >> 6;
    const int mbase = (wv & 1) << 6;     // px half within tile
    const int nbase = (wv >> 1) << 6;    // oc half within tile
    const int quad  = lane >> 4;
    const int l15   = lane & 15;

    const int oc0 = bx << 7;
    const int px0 = by << 7;
    const u16* inb  = in  + (size_t)bz * 256 * HW;
    u16*       outb = out + (size_t)bz * 256 * HW;

    const int spx = t & 127;             // staged row (px for A, oc for B)
    const int sq  = t >> 7;              // 16-ic half
    const int gx = (px0 + spx) & (W - 1);
    const int gy = (px0 + spx) >> LOGW;

    // swizzled LDS offsets: row r, chunk c (8 u16) at r*32 + ((c^((r>>1)&3))<<3)
    const int sw  = (spx >> 1) & 3;
    const int aw0 = spx * 32 + (((sq << 1) ^ sw) << 3);
    const int aw1 = spx * 32 + ((((sq << 1) | 1) ^ sw) << 3);
    int prd[4], ord_[4];
    #pragma unroll
    for (int i = 0; i < 4; ++i) {
        int ra = mbase + (i << 4) + l15;          // px frag rows (As)
        prd[i] = ra * 32 + ((quad ^ ((ra >> 1) & 3)) << 3);
        int rb = nbase + (i << 4) + l15;          // oc frag rows (Bs)
        ord_[i] = rb * 32 + ((quad ^ ((rb >> 1) & 3)) << 3);
    }

    f32x4 acc[4][4];
    #pragma unroll
    for (int i = 0; i < 4; ++i)
        #pragma unroll
        for (int j = 0; j < 4; ++j) acc[i][j] = (f32x4)0.f;

    // staging state
    alignas(16) u16 av[16];
    alignas(16) u16 bv[16];
    const u16* srcBb = wTo + (size_t)(oc0 + spx) * 256 + sq * 16;
    int aofs = 0;            // A element offset for current tap (w/o ic)
    bool valid = false;

    auto setTap = [&](int dh, int dwt) {
        const int ys = gy + dh - 1;
        const int xs = gx + dwt - 1;
        valid = ((unsigned)ys < (unsigned)H) && ((unsigned)xs < (unsigned)W);
        aofs = ((ys * W + xs) << 8) + sq * 16;
    };
    auto issue = [&](int k3, int ic0) {
        if (valid) {
            const u16* p = inb + aofs + ic0;
            *(uint4*)&av[0] = *(const uint4*)(p);
            *(uint4*)&av[8] = *(const uint4*)(p + 8);
        } else {
            #pragma unroll
            for (int s = 0; s < 16; ++s) av[s] = 0;
        }
        const u16* q = srcBb + k3 * 65536 + ic0;
        *(uint4*)&bv[0] = *(const uint4*)(q);
        *(uint4*)&bv[8] = *(const uint4*)(q + 8);
    };

    setTap(0, 0);
    issue(0, 0);
    int k3 = 0, ic0 = 0, dh = 0, dwt = 0;
    for (int it = 0; it < 72; ++it) {
        __syncthreads();                 // prior frag reads done
        *(uint4*)&As[aw0] = *(const uint4*)&av[0];
        *(uint4*)&As[aw1] = *(const uint4*)&av[8];
        *(uint4*)&Bs[aw0] = *(const uint4*)&bv[0];
        *(uint4*)&Bs[aw1] = *(const uint4*)&bv[8];
        __syncthreads();                 // staged data visible
        if (it < 71) {                   // prefetch next chunk NOW
            ic0 += 32;
            if (ic0 == 256) {
                ic0 = 0; ++k3;
                if (++dwt == 3) { dwt = 0; ++dh; }
                setTap(dh, dwt);
            }
            issue(k3, ic0);
        }
        __builtin_amdgcn_sched_barrier(0);   // pin prefetch above MFMA block

        short8 pf[4], of[4];
        #pragma unroll
        for (int i = 0; i < 4; ++i) pf[i] = *(const short8*)&As[prd[i]];
        #pragma unroll
        for (int j = 0; j < 4; ++j) of[j] = *(const short8*)&Bs[ord_[j]];
        #pragma unroll
        for (int i = 0; i < 4; ++i)
            #pragma unroll
            for (int j = 0; j < 4; ++j)
                acc[i][j] = __builtin_amdgcn_mfma_f32_16x16x32_bf16(
                    of[j], pf[i], acc[i][j], 0, 0, 0);
    }

    // epilogue: BN+ReLU, channels-last ushort4 stores.
    // acc[i][j]: px = px0+mbase+(i<<4)+l15 (lane axis),
    //            oc = oc0+nbase+(j<<4)+(quad<<2)+r (reg axis) [verified r5].
    float sc[4][4], sh[4][4];
    #pragma unroll
    for (int j = 0; j < 4; ++j) {
        const int f = oc0 + nbase + (j << 4) + (quad << 2);
        #pragma unroll
        for (int r = 0; r < 4; ++r) {
            float g  = ldx(bnp, f + r, fl);
            float be = ldx(bnp, 256 + f + r, fl);
            float mn = ldx(bnp, 512 + f + r, fl);
            float vv = ldx(bnp, 768 + f + r, fl);
            sc[j][r] = g / sqrtf(vv + 1e-5f);
            sh[j][r] = be - mn * sc[j][r];
        }
    }
    #pragma unroll
    for (int i = 0; i < 4; ++i) {
        const int px = px0 + mbase + (i << 4) + l15;
        u16* op = outb + (size_t)px * 256 + oc0 + nbase + (quad << 2);
        #pragma unroll
        for (int j = 0; j < 4; ++j) {
            f32x4 a = acc[i][j];
            ushort4 o;
            o.x = f2b(fmaxf(a[0] * sc[j][0] + sh[j][0], 0.f));
            o.y = f2b(fmaxf(a[1] * sc[j][1] + sh[j][1], 0.f));
            o.z = f2b(fmaxf(a[2] * sc[j][2] + sh[j][2], 0.f));
            o.w = f2b(fmaxf(a[3] * sc[j][3] + sh[j][3], 0.f));
            *(ushort4*)(op + (j << 4)) = o;
        }
    }
}

// ---------------------------------------------------------------------------
// Head: 3x3 conv 256->1, channels-last input, one thread per output px.
__global__ __launch_bounds__(256) void k_head(const u16* __restrict__ in,
                                              const u16* __restrict__ wH,
                                              const void* __restrict__ bias,
                                              const int* __restrict__ flag,
                                              void* __restrict__ outp,
                                              int b0)
{
    const int fl = *flag;
    const int px = blockIdx.x * 256 + threadIdx.x;    // 0..16383
    const u16* inb = in + (size_t)blockIdx.y * 16384 * 256;
    const int x = px & 127, y = px >> 7;
    float acc = ldx(bias, 0, fl);
    #pragma unroll
    for (int kh = 0; kh < 3; ++kh) {
        int yy = y + kh - 1;
        if (yy < 0 || yy >= 128) continue;
        #pragma unroll
        for (int kw = 0; kw < 3; ++kw) {
            int xx = x + kw - 1;
            if (xx < 0 || xx >= 128) continue;
            const u16* p  = inb + (size_t)((yy << 7) + xx) * 256;
            const u16* wp = wH + (kh * 3 + kw) * 256;
            #pragma unroll 4
            for (int icc = 0; icc < 32; ++icc) {
                short8 v = *(const short8*)(p + icc * 8);
                short8 wv8 = *(const short8*)(wp + icc * 8);
                #pragma unroll
                for (int s = 0; s < 8; ++s)
                    acc = fmaf(b2f((u16)v[s]), b2f((u16)wv8[s]), acc);
            }
        }
    }
    int out_ofs = (b0 + blockIdx.y) * 16384 + px;
    if (fl) ((float*)outp)[out_ofs] = acc;
    else    ((u16*)outp)[out_ofs] = f2b(acc);
}

// ---------------------------------------------------------------------------
extern "C" void kernel_launch(void* const* d_in, const int* in_sizes, int n_in,
                              void* d_out, int out_size, void* d_ws, size_t ws_size,
                              hipStream_t stream) {
    (void)in_sizes; (void)n_in; (void)out_size;
    const void* f1     = d_in[0];
    const void* f2     = d_in[1];
    const void* f3     = d_in[2];
    const void* f4     = d_in[3];
    const void* proj_w = d_in[4];
    const void* lwp    = d_in[5];
    const void* dw_w   = d_in[6];
    const void* bn_enh = d_in[7];
    const void* ow1    = d_in[8];
    const void* ob1    = d_in[9];
    const void* cw1    = d_in[10];
    const void* bn1    = d_in[11];
    const void* ow2    = d_in[12];
    const void* ob2    = d_in[13];
    const void* cw2    = d_in[14];
    const void* bn2    = d_in[15];
    const void* out_w  = d_in[16];
    const void* out_b  = d_in[17];

    // stage-2 chunking by available workspace (ws_size is host-visible)
    const int nb = (ws_size >= 81592320ull) ? 4
                 : (ws_size >= 48037888ull) ? 2 : 1;

    // ---- workspace layout (channels-last intermediates) ----
    char* ws = (char*)d_ws;
    int*   flag = (int*)  (ws + 0);
    u16*   wH   = (u16*)  (ws + 4096);        // 4608 B head weights
    u16*   wT1  = (u16*)  (ws + 65536);
    u16*   wT2  = (u16*)  (ws + 1245184);
    u16*   pwT  = (u16*)  (ws + 2424832);
    u16*   c1   = (u16*)  (ws + 3997696);     // 8 MB bf16 (4, 4096px, 256)
    float* o2   = (float*)(ws + 12386304);    // 2 MB f32 (4,32,64,64)
    u16*   up2c = (u16*)  (ws + 14483456);    // nb*8 MB bf16 (nb,16384px,256)
    u16*   c2c  = (u16*)  (ws + 14483456 + (size_t)nb * 8388608);  // nb*8 MB
    float* gbuf = (float*)(ws + 3997696);     // 16 MB, dead before c1/o2/up1
    float* x0   = (float*)(ws + 20774912);    // 4 MB (dead before up2c/c2c)
    float* x1   = (float*)(ws + 24969216);    // 4 MB
    float* o1   = (float*)(ws + 29163520);    // 0.5 MB
    u16*   up1  = (u16*)  (ws + 12386304);    // 8 MB, overlaps o2 (dead then)

    // 0) dtype detect + weight transposes
    k_detect<<<1, 256, 0, stream>>>(f1, flag);
    k_wt<<<2304, 256, 0, stream>>>(cw1, wT1, flag);
    k_wt<<<2304, 256, 0, stream>>>(cw2, wT2, flag);
    k_pwt<<<3072, 256, 0, stream>>>(proj_w, pwT, flag);
    k_wh<<<9, 256, 0, stream>>>(out_w, wH, flag);

    // 1) weighted fusion (MFMA) -> gbuf, then sum -> x0 (channels-last)
    k_fgemm<<<dim3(2, 8, 16), 256, 0, stream>>>(f1, f2, f3, f4, pwT, lwp, flag, gbuf);
    k_fsum<<<4096, 256, 0, stream>>>(gbuf, x0);

    // 2) spatial detail enhancer -> x1 f32 (channels-last)
    k_dw<<<4096, 256, 0, stream>>>(x0, dw_w, bn_enh, flag, x1);

    // 3) dysample #1 (32->64) + conv1 -> c1 bf16 (all 4 batches)
    k_offs<false><<<512, 256, 0, stream>>>(x1, ow1, ob1, flag, o1, 32 * 32);
    k_sample<false><<<16384, 256, 0, stream>>>(x1, o1, up1, 32, 32, 6);
    k_cm5<6><<<dim3(2, 32, 4), 256, 0, stream>>>(up1, wT1, bn1, flag, c1, 64);

    // 4) offsets for stage 2 (all batches)
    k_offs<true><<<2048, 256, 0, stream>>>(c1, ow2, ob2, flag, o2, 64 * 64);

    // 5) chunked: dysample #2 (64->128) + conv2 + head
    for (int b0 = 0; b0 < 4; b0 += nb) {
        const u16*   c1b = c1 + (size_t)b0 * 4096 * 256;
        const float* o2b = o2 + (size_t)b0 * 32 * 4096;
        k_sample<true><<<16384 * nb, 256, 0, stream>>>(c1b, o2b, up2c, 64, 64, 7);
        k_cm5<7><<<dim3(2, 128, nb), 256, 0, stream>>>(up2c, wT2, bn2, flag,
                                                       c2c, 128);
        k_head<<<dim3(64, nb), 256, 0, stream>>>(c2c, wH, out_b, flag, d_out, b0);
    }
}

// Round 7
// 522.669 us; speedup vs baseline: 1.6489x; 1.3493x over previous
//
#include <hip/hip_runtime.h>
#include <math.h>

using u16 = unsigned short;
typedef __attribute__((ext_vector_type(8))) short short8;
typedef __attribute__((ext_vector_type(4))) float f32x4;

__device__ __forceinline__ float b2f(u16 u) {
    union { unsigned int i; float f; } v; v.i = ((unsigned int)u) << 16; return v.f;
}
__device__ __forceinline__ u16 f2b(float f) {
    union { float f; unsigned int i; } v; v.f = f;
    unsigned int x = v.i;
    return (u16)((x + 0x7FFFu + ((x >> 16) & 1u)) >> 16);
}
// dtype-adaptive external load: fl=1 -> f32, fl=0 -> bf16
__device__ __forceinline__ float ldx(const void* p, long long i, int fl) {
    return fl ? ((const float*)p)[i] : b2f(((const u16*)p)[i]);
}

// ---------------------------------------------------------------------------
// Detect input dtype: read first 4096 u16 of f1 as bf16. flag=1 means f32.
__global__ __launch_bounds__(256) void k_detect(const void* p, int* flag) {
    __shared__ float m[256];
    int t = threadIdx.x;
    const u16* q = (const u16*)p;
    float lm = 0.f;
    for (int j = 0; j < 16; ++j) {
        float v = b2f(q[t * 16 + j]);
        float a = fabsf(v);
        if (!(a <= 1e30f)) a = 1e31f;   // NaN/Inf -> huge
        lm = fmaxf(lm, a);
    }
    m[t] = lm;
    __syncthreads();
    if (t == 0) {
        float mm = 0.f;
        for (int i = 0; i < 256; ++i) mm = fmaxf(mm, m[i]);
        *flag = (mm > 1000.f) ? 1 : 0;
    }
}

// ---------------------------------------------------------------------------
// Weight transpose: conv w (OC=256, IC=256, 3, 3) -> wTo[tap][icc][oc][ic32]
// bf16, so a [128oc][32ic] staging chunk is one contiguous 8KB span.
__global__ __launch_bounds__(256) void k_wt(const void* __restrict__ w,
                                            u16* __restrict__ wTo,
                                            const int* __restrict__ flag) {
    int fl = *flag;
    int idx = blockIdx.x * 256 + threadIdx.x;   // 589824 total
    int ici = idx & 31;
    int oc  = (idx >> 5) & 255;
    int icc = (idx >> 13) & 7;
    int k   = idx >> 16;                        // 0..8
    int ic  = (icc << 5) + ici;
    long long s = (oc * 256 + ic) * 9 + k;
    wTo[idx] = fl ? f2b(((const float*)w)[s]) : ((const u16*)w)[s];
}

// ---------------------------------------------------------------------------
// proj_w transpose: (L=4, C=768, F=256) -> pwT[l][f][c] bf16
__global__ __launch_bounds__(256) void k_pwt(const void* __restrict__ w,
                                             u16* __restrict__ pwT,
                                             const int* __restrict__ flag) {
    int fl = *flag;
    int idx = blockIdx.x * 256 + threadIdx.x;   // 786432 total
    int c = idx % 768;
    int f = (idx / 768) & 255;
    int l = idx / (768 * 256);
    long long s = ((long long)l * 768 + c) * 256 + f;
    pwT[idx] = fl ? f2b(((const float*)w)[s]) : ((const u16*)w)[s];
}

// ---------------------------------------------------------------------------
// Head-weight transpose (1,256,3,3) -> wH[k][ic] bf16.
__global__ __launch_bounds__(256) void k_wh(const void* __restrict__ w,
                                            u16* __restrict__ wH,
                                            const int* __restrict__ flag) {
    int fl = *flag;
    int k = blockIdx.x;            // 0..8
    int ic = threadIdx.x;
    wH[k * 256 + ic] = fl ? f2b(((const float*)w)[ic * 9 + k])
                          : ((const u16*)w)[ic * 9 + k];
}

// ---------------------------------------------------------------------------
// Fusion pass 1 (MFMA, BK=32): per (b,l) 128px x 128f GEMM over K=768,
// epilogue gelu * softmax(lw)[l] -> gbuf[(l,b)][px][f] f32 (channels-last).
// (unchanged from r6 -- verified correct)
__global__ __launch_bounds__(256) void k_fgemm(
    const void* __restrict__ f1, const void* __restrict__ f2,
    const void* __restrict__ f3, const void* __restrict__ f4,
    const u16* __restrict__ pwT, const void* __restrict__ lwp,
    const int* __restrict__ flag, float* __restrict__ gbuf)
{
    __shared__ u16 As[128 * 32];
    const int fl = *flag;
    const int t    = threadIdx.x;
    const int lane = t & 63;
    const int wv   = t >> 6;
    const int mbase = (wv & 1) << 6;
    const int nbase = (wv >> 1) << 6;
    const int quad  = lane >> 4;
    const int l15   = lane & 15;

    const int f0 = blockIdx.x << 7;
    const int m0 = blockIdx.y << 7;
    const int b  = blockIdx.z >> 2;
    const int l  = blockIdx.z & 3;
    const void* fp = (l == 0) ? f1 : (l == 1) ? f2 : (l == 2) ? f3 : f4;

    float w0 = ldx(lwp, 0, fl), w1 = ldx(lwp, 1, fl);
    float w2 = ldx(lwp, 2, fl), w3 = ldx(lwp, 3, fl);
    float mx = fmaxf(fmaxf(w0, w1), fmaxf(w2, w3));
    float e0 = expf(w0 - mx), e1 = expf(w1 - mx), e2 = expf(w2 - mx), e3 = expf(w3 - mx);
    float es = e0 + e1 + e2 + e3;
    float lwl = ((l == 0) ? e0 : (l == 1) ? e1 : (l == 2) ? e2 : e3) / es;

    const int spx = t & 127;      // px row staged
    const int sq  = t >> 7;       // which 16-k half

    const int sw  = (spx >> 1) & 3;
    const int aw0 = spx * 32 + (((sq << 1) ^ sw) << 3);
    const int aw1 = spx * 32 + ((((sq << 1) | 1) ^ sw) << 3);
    int ard[4];
    #pragma unroll
    for (int i = 0; i < 4; ++i) {
        int ra = mbase + (i << 4) + l15;
        ard[i] = ra * 32 + ((quad ^ ((ra >> 1) & 3)) << 3);
    }
    // B direct-load row offsets
    const u16* srcBb = pwT + (size_t)l * 196608 + (size_t)f0 * 768 + (quad << 3);
    int bofs[4];
    #pragma unroll
    for (int j = 0; j < 4; ++j)
        bofs[j] = (nbase + (j << 4) + l15) * 768;

    f32x4 acc[4][4];
    #pragma unroll
    for (int i = 0; i < 4; ++i)
        #pragma unroll
        for (int j = 0; j < 4; ++j) acc[i][j] = (f32x4)0.f;

    const size_t abase = (size_t)b * 768 * 1024 + m0 + spx;

    alignas(16) u16 av[16];
    float afv[16];
    auto issue = [&](int k0) {
        if (fl) {
            #pragma unroll
            for (int s = 0; s < 16; ++s)
                afv[s] = ((const float*)fp)[abase + (size_t)(k0 + sq * 16 + s) * 1024];
        } else {
            #pragma unroll
            for (int s = 0; s < 16; ++s)
                av[s] = ((const u16*)fp)[abase + (size_t)(k0 + sq * 16 + s) * 1024];
        }
    };

    issue(0);
    for (int k0 = 0; k0 < 768; k0 += 32) {
        __syncthreads();
        if (fl) {
            #pragma unroll
            for (int s = 0; s < 16; ++s) av[s] = f2b(afv[s]);
        }
        *(uint4*)&As[aw0] = *(const uint4*)&av[0];
        *(uint4*)&As[aw1] = *(const uint4*)&av[8];
        __syncthreads();
        if (k0 < 736) issue(k0 + 32);
        __builtin_amdgcn_sched_barrier(0);

        short8 af[4], bf[4];
        #pragma unroll
        for (int i = 0; i < 4; ++i) af[i] = *(const short8*)&As[ard[i]];
        #pragma unroll
        for (int j = 0; j < 4; ++j) bf[j] = *(const short8*)(srcBb + bofs[j] + k0);
        #pragma unroll
        for (int i = 0; i < 4; ++i)
            #pragma unroll
            for (int j = 0; j < 4; ++j)
                acc[i][j] = __builtin_amdgcn_mfma_f32_16x16x32_bf16(
                    bf[j], af[i], acc[i][j], 0, 0, 0);
    }

    // epilogue: gelu * lw[l]; channels-last store [px][f..f+3]
    #pragma unroll
    for (int j = 0; j < 4; ++j) {
        const int fb = f0 + nbase + (j << 4) + (quad << 2);
        #pragma unroll
        for (int i = 0; i < 4; ++i) {
            const int px = m0 + mbase + (i << 4) + l15;
            f32x4 a = acc[i][j];
            float4 o;
            o.x = lwl * 0.5f * a[0] * (1.f + erff(a[0] * 0.70710678118654752f));
            o.y = lwl * 0.5f * a[1] * (1.f + erff(a[1] * 0.70710678118654752f));
            o.z = lwl * 0.5f * a[2] * (1.f + erff(a[2] * 0.70710678118654752f));
            o.w = lwl * 0.5f * a[3] * (1.f + erff(a[3] * 0.70710678118654752f));
            *(float4*)(gbuf + ((size_t)((l << 2) + b) * 1024 + px) * 256 + fb) = o;
        }
    }
}

// Fusion pass 2: x0 = sum over 4 layer slabs (layout-agnostic).
__global__ __launch_bounds__(256) void k_fsum(const float* __restrict__ gbuf,
                                              float* __restrict__ x0)
{
    int idx = blockIdx.x * 256 + threadIdx.x;   // 1048576 total
    x0[idx] = gbuf[idx] + gbuf[1048576 + idx]
            + gbuf[2097152 + idx] + gbuf[3145728 + idx];
}

// ---------------------------------------------------------------------------
// Depthwise 3x3 + BN + residual ReLU, channels-last (4,1024px,256) f32 -> f32
__global__ __launch_bounds__(256) void k_dw(const float* __restrict__ x0,
                                            const void* __restrict__ dww,
                                            const void* __restrict__ bnp,
                                            const int* __restrict__ flag,
                                            float* __restrict__ x1)
{
    const int fl = *flag;
    int idx = blockIdx.x * 256 + threadIdx.x;     // 1048576 total
    int f   = idx & 255;
    int bpx = idx >> 8;
    int n   = bpx & 1023;
    int bb  = bpx >> 10;
    int h = n >> 5, w = n & 31;
    const float* xb = x0 + ((size_t)(bb << 10)) * 256;
    float acc = 0.f;
    #pragma unroll
    for (int kh = 0; kh < 3; ++kh) {
        int y = h + kh - 1;
        if (y < 0 || y >= 32) continue;
        #pragma unroll
        for (int kw = 0; kw < 3; ++kw) {
            int x = w + kw - 1;
            if (x < 0 || x >= 32) continue;
            acc += xb[(size_t)((y << 5) + x) * 256 + f]
                 * ldx(dww, f * 9 + kh * 3 + kw, fl);
        }
    }
    float g  = ldx(bnp, f, fl);
    float be = ldx(bnp, 256 + f, fl);
    float mn = ldx(bnp, 512 + f, fl);
    float vv = ldx(bnp, 768 + f, fl);
    float scale = g / sqrtf(vv + 1e-5f);
    float o = (acc - mn) * scale + be + x0[idx];
    x1[idx] = fmaxf(o, 0.f);
}

// ---------------------------------------------------------------------------
// 1x1 offset conv, channels-last act (B,HW,256) -> off (B,32,HW) f32.
template<bool ACT_BF16>
__global__ __launch_bounds__(256) void k_offs(const void* __restrict__ actv,
                                              const void* __restrict__ w,
                                              const void* __restrict__ bias,
                                              const int* __restrict__ flag,
                                              float* __restrict__ off,
                                              int HW)
{
    const int fl = *flag;
    int idx = blockIdx.x * 256 + threadIdx.x;     // B*32*HW total
    int pos = idx % HW;
    int oc  = (idx / HW) & 31;
    int b   = idx / (32 * HW);
    float acc = 0.f;
    if (ACT_BF16) {
        const u16* ap = (const u16*)actv + ((size_t)b * HW + pos) * 256;
        #pragma unroll 4
        for (int icc = 0; icc < 32; ++icc) {
            short8 v = *(const short8*)(ap + icc * 8);
            #pragma unroll
            for (int s = 0; s < 8; ++s)
                acc = fmaf(b2f((u16)v[s]), ldx(w, oc * 256 + icc * 8 + s, fl), acc);
        }
    } else {
        const float* ap = (const float*)actv + ((size_t)b * HW + pos) * 256;
        #pragma unroll 4
        for (int icc = 0; icc < 32; ++icc) {
            f32x4 v0 = *(const f32x4*)(ap + icc * 8);
            f32x4 v1 = *(const f32x4*)(ap + icc * 8 + 4);
            #pragma unroll
            for (int s = 0; s < 4; ++s) {
                acc = fmaf(v0[s], ldx(w, oc * 256 + icc * 8 + s, fl), acc);
                acc = fmaf(v1[s], ldx(w, oc * 256 + icc * 8 + 4 + s, fl), acc);
            }
        }
    }
    off[idx] = acc + ldx(bias, oc, fl);
}

// ---------------------------------------------------------------------------
// DySample grid sample x2. Input channels-last [px][256]; output channel-
// BLOCKED [icc8][HWo][32] bf16 (so the conv's A staging chunks are contiguous).
template<bool ACT_BF16>
__global__ __launch_bounds__(256) void k_sample(const void* __restrict__ actv,
                                                const float* __restrict__ off,
                                                u16* __restrict__ out,
                                                int H, int W, int logWo)
{
    const int Wo = W << 1, Ho = H << 1;
    const int HW = H * W;
    const int HWo = Ho * Wo;
    int idx = blockIdx.x * 256 + threadIdx.x;
    int c  = idx & 255;
    int q  = idx >> 8;
    int wo = q & (Wo - 1);
    int ho = (q >> logWo) & (Ho - 1);
    int b  = q >> (logWo << 1);            // square: logHo == logWo
    int pxo = (ho << logWo) + wo;
    int g  = c >> 6;
    int h = ho >> 1, a = ho & 1, w = wo >> 1, bb = wo & 1;
    int och = g * 4 + a * 2 + bb;
    size_t obase = ((size_t)b * 32 + och) * HW + h * W + w;
    float offx = off[obase];
    float offy = off[obase + (size_t)16 * HW];
    float xp = (float)w + (bb ? 0.25f : -0.25f) + 0.25f * offx;
    float yp = (float)h + (a  ? 0.25f : -0.25f) + 0.25f * offy;
    xp = fminf(fmaxf(xp, 0.f), (float)(W - 1));
    yp = fminf(fmaxf(yp, 0.f), (float)(H - 1));
    float xf = floorf(xp), yf = floorf(yp);
    float wx = xp - xf, wy = yp - yf;
    int x0i = (int)xf; x0i = max(0, min(x0i, W - 1));
    int y0i = (int)yf; y0i = max(0, min(y0i, H - 1));
    int x1i = min(x0i + 1, W - 1);
    int y1i = min(y0i + 1, H - 1);
    float v00, v01, v10, v11;
    if (ACT_BF16) {
        const u16* ap = (const u16*)actv + (size_t)b * HW * 256;
        v00 = b2f(ap[(size_t)(y0i * W + x0i) * 256 + c]);
        v01 = b2f(ap[(size_t)(y0i * W + x1i) * 256 + c]);
        v10 = b2f(ap[(size_t)(y1i * W + x0i) * 256 + c]);
        v11 = b2f(ap[(size_t)(y1i * W + x1i) * 256 + c]);
    } else {
        const float* ap = (const float*)actv + (size_t)b * HW * 256;
        v00 = ap[(size_t)(y0i * W + x0i) * 256 + c];
        v01 = ap[(size_t)(y0i * W + x1i) * 256 + c];
        v10 = ap[(size_t)(y1i * W + x0i) * 256 + c];
        v11 = ap[(size_t)(y1i * W + x1i) * 256 + c];
    }
    float r = v00 * (1.f - wy) * (1.f - wx) + v01 * (1.f - wy) * wx
            + v10 * wy * (1.f - wx) + v11 * wy * wx;
    // blocked store: [b][c>>5][pxo][c&31]
    out[((size_t)b << 8) * HWo + (((size_t)(c >> 5) * HWo + pxo) << 5) + (c & 31)]
        = f2b(r);
}

// ---------------------------------------------------------------------------
// MFMA implicit-GEMM 3x3 conv 256->256 + BN + ReLU.
// Input channel-BLOCKED [icc8][HW][32] bf16; output channels-last [px][256].
// r7: identical 2-barrier structure/geometry to r6, but every staging load is
// CONTIGUOUS: an A (or B) chunk [128 rows][32 ic] is one 8KB span; each thread
// does 2+2 uint4 loads with lanes contiguous -> 16 lines/wave-instr instead of
// 64 (r6's 512B-stride scatter was the per-CU TA/L2 transaction wall: conv1
// 1 blk/CU == conv2 4 blk/CU == 263us). Tap shift = +-32-elem offset of the
// span; OOB/x-wrap rows zeroed via precomputed per-group validity.
// grid: (2 oc-halves, HW/128 px-tiles, batches); nwg % 8 == 0 always.
template<int LOGW>
__global__ __launch_bounds__(256) void k_cb(const u16* __restrict__ in,
                                            const u16* __restrict__ wTo,
                                            const void* __restrict__ bnp,
                                            const int* __restrict__ flag,
                                            u16* __restrict__ out,
                                            int H)
{
    constexpr int W = 1 << LOGW;
    __shared__ u16 As[128 * 32];   // [row][32 ic], octet-XOR swizzled
    __shared__ u16 Bs[128 * 32];   // [oc][32 ic]
    const int fl = *flag;
    const int HW = H * W;

    // chunked XCD swizzle (bijective; nwg multiple of 8)
    const unsigned nwg  = gridDim.x * gridDim.y * gridDim.z;
    const unsigned flat = (blockIdx.z * gridDim.y + blockIdx.y) * gridDim.x
                        + blockIdx.x;
    const unsigned wid  = (flat & 7u) * (nwg >> 3) + (flat >> 3);
    const int bx = wid & 1;                        // gridDim.x == 2
    const unsigned rem = wid >> 1;
    const int lgy = __ffs((int)gridDim.y) - 1;     // gridDim.y is pow2
    const int by = rem & (gridDim.y - 1);
    const int bz = rem >> lgy;

    const int t    = threadIdx.x;
    const int lane = t & 63;
    const int wv   = t >> 6;
    const int mbase = (wv & 1) << 6;     // px half within tile
    const int nbase = (wv >> 1) << 6;    // oc half within tile
    const int quad  = lane >> 4;
    const int l15   = lane & 15;

    const int oc0 = bx << 7;
    const int px0 = by << 7;
    const u16* inb  = in  + (size_t)bz * 256 * HW;   // [icc][HW][32]
    u16*       outb = out + (size_t)bz * 256 * HW;   // [px][256]

    // staging: thread t handles groups g0 = t, g1 = t + 256 (8-u16 groups)
    // group g -> row r = g>>2 (0..127), octet o = t&3
    const int to  = t & 3;
    const int r0_ = t >> 2;
    int al[2];
    #pragma unroll
    for (int g = 0; g < 2; ++g) {
        int r = r0_ + (g << 6);
        al[g] = r * 32 + ((to ^ ((r >> 1) & 3)) << 3);
    }

    // fragment read offsets (same geometry as r6; 0 conflicts measured)
    int prd[4], ord_[4];
    #pragma unroll
    for (int i = 0; i < 4; ++i) {
        int ra = mbase + (i << 4) + l15;
        prd[i] = ra * 32 + ((quad ^ ((ra >> 1) & 3)) << 3);
        int rb = nbase + (i << 4) + l15;
        ord_[i] = rb * 32 + ((quad ^ ((rb >> 1) & 3)) << 3);
    }

    f32x4 acc[4][4];
    #pragma unroll
    for (int i = 0; i < 4; ++i)
        #pragma unroll
        for (int j = 0; j < 4; ++j) acc[i][j] = (f32x4)0.f;

    // staging state
    uint4 av0, av1, bq0, bq1;
    int  aofs[2];
    bool aval[2];

    auto setTap = [&](int dh, int dwt) {
        const int shift = (dh - 1) * W + (dwt - 1);
        #pragma unroll
        for (int g = 0; g < 2; ++g) {
            const int r   = r0_ + (g << 6);
            const int opx = px0 + r;
            const int ox  = opx & (W - 1);
            const int q   = opx + shift;
            aval[g] = (q >= 0) && (q < HW)
                   && !(dwt == 0 && ox == 0) && !(dwt == 2 && ox == W - 1);
            aofs[g] = (q << 5) + (to << 3);
        }
    };
    auto issue = [&](int k3, int icc) {
        const int icb = icc * (HW << 5);
        const uint4 z4 = {0u, 0u, 0u, 0u};
        av0 = aval[0] ? *(const uint4*)(inb + icb + aofs[0]) : z4;
        av1 = aval[1] ? *(const uint4*)(inb + icb + aofs[1]) : z4;
        const u16* bp = wTo + ((((k3 << 3) + icc) << 13) + (oc0 << 5)) + (t << 3);
        bq0 = *(const uint4*)(bp);
        bq1 = *(const uint4*)(bp + 2048);
    };

    setTap(0, 0);
    issue(0, 0);
    int k3 = 0, icc = 0, dh = 0, dwt = 0;
    for (int it = 0; it < 72; ++it) {
        __syncthreads();                 // prior frag reads done
        *(uint4*)&As[al[0]] = av0;
        *(uint4*)&As[al[1]] = av1;
        *(uint4*)&Bs[al[0]] = bq0;
        *(uint4*)&Bs[al[1]] = bq1;
        __syncthreads();                 // staged data visible
        if (it < 71) {                   // prefetch next chunk NOW
            if (++icc == 8) {
                icc = 0; ++k3;
                if (++dwt == 3) { dwt = 0; ++dh; }
                setTap(dh, dwt);
            }
            issue(k3, icc);
        }
        __builtin_amdgcn_sched_barrier(0);   // pin prefetch above MFMA block

        short8 pf[4], of[4];
        #pragma unroll
        for (int i = 0; i < 4; ++i) pf[i] = *(const short8*)&As[prd[i]];
        #pragma unroll
        for (int j = 0; j < 4; ++j) of[j] = *(const short8*)&Bs[ord_[j]];
        #pragma unroll
        for (int i = 0; i < 4; ++i)
            #pragma unroll
            for (int j = 0; j < 4; ++j)
                acc[i][j] = __builtin_amdgcn_mfma_f32_16x16x32_bf16(
                    of[j], pf[i], acc[i][j], 0, 0, 0);
    }

    // epilogue: BN+ReLU, channels-last ushort4 stores (verified r5/r6):
    // px = px0+mbase+(i<<4)+l15 (lane axis), oc = oc0+nbase+(j<<4)+(quad<<2)+r.
    float sc[4][4], sh[4][4];
    #pragma unroll
    for (int j = 0; j < 4; ++j) {
        const int f = oc0 + nbase + (j << 4) + (quad << 2);
        #pragma unroll
        for (int r = 0; r < 4; ++r) {
            float g  = ldx(bnp, f + r, fl);
            float be = ldx(bnp, 256 + f + r, fl);
            float mn = ldx(bnp, 512 + f + r, fl);
            float vv = ldx(bnp, 768 + f + r, fl);
            sc[j][r] = g / sqrtf(vv + 1e-5f);
            sh[j][r] = be - mn * sc[j][r];
        }
    }
    #pragma unroll
    for (int i = 0; i < 4; ++i) {
        const int px = px0 + mbase + (i << 4) + l15;
        u16* op = outb + (size_t)px * 256 + oc0 + nbase + (quad << 2);
        #pragma unroll
        for (int j = 0; j < 4; ++j) {
            f32x4 a = acc[i][j];
            ushort4 o;
            o.x = f2b(fmaxf(a[0] * sc[j][0] + sh[j][0], 0.f));
            o.y = f2b(fmaxf(a[1] * sc[j][1] + sh[j][1], 0.f));
            o.z = f2b(fmaxf(a[2] * sc[j][2] + sh[j][2], 0.f));
            o.w = f2b(fmaxf(a[3] * sc[j][3] + sh[j][3], 0.f));
            *(ushort4*)(op + (j << 4)) = o;
        }
    }
}

// ---------------------------------------------------------------------------
// Head: 3x3 conv 256->1, channels-last input, one thread per output px.
__global__ __launch_bounds__(256) void k_head(const u16* __restrict__ in,
                                              const u16* __restrict__ wH,
                                              const void* __restrict__ bias,
                                              const int* __restrict__ flag,
                                              void* __restrict__ outp,
                                              int b0)
{
    const int fl = *flag;
    const int px = blockIdx.x * 256 + threadIdx.x;    // 0..16383
    const u16* inb = in + (size_t)blockIdx.y * 16384 * 256;
    const int x = px & 127, y = px >> 7;
    float acc = ldx(bias, 0, fl);
    #pragma unroll
    for (int kh = 0; kh < 3; ++kh) {
        int yy = y + kh - 1;
        if (yy < 0 || yy >= 128) continue;
        #pragma unroll
        for (int kw = 0; kw < 3; ++kw) {
            int xx = x + kw - 1;
            if (xx < 0 || xx >= 128) continue;
            const u16* p  = inb + (size_t)((yy << 7) + xx) * 256;
            const u16* wp = wH + (kh * 3 + kw) * 256;
            #pragma unroll 4
            for (int icc = 0; icc < 32; ++icc) {
                short8 v = *(const short8*)(p + icc * 8);
                short8 wv8 = *(const short8*)(wp + icc * 8);
                #pragma unroll
                for (int s = 0; s < 8; ++s)
                    acc = fmaf(b2f((u16)v[s]), b2f((u16)wv8[s]), acc);
            }
        }
    }
    int out_ofs = (b0 + blockIdx.y) * 16384 + px;
    if (fl) ((float*)outp)[out_ofs] = acc;
    else    ((u16*)outp)[out_ofs] = f2b(acc);
}

// ---------------------------------------------------------------------------
extern "C" void kernel_launch(void* const* d_in, const int* in_sizes, int n_in,
                              void* d_out, int out_size, void* d_ws, size_t ws_size,
                              hipStream_t stream) {
    (void)in_sizes; (void)n_in; (void)out_size;
    const void* f1     = d_in[0];
    const void* f2     = d_in[1];
    const void* f3     = d_in[2];
    const void* f4     = d_in[3];
    const void* proj_w = d_in[4];
    const void* lwp    = d_in[5];
    const void* dw_w   = d_in[6];
    const void* bn_enh = d_in[7];
    const void* ow1    = d_in[8];
    const void* ob1    = d_in[9];
    const void* cw1    = d_in[10];
    const void* bn1    = d_in[11];
    const void* ow2    = d_in[12];
    const void* ob2    = d_in[13];
    const void* cw2    = d_in[14];
    const void* bn2    = d_in[15];
    const void* out_w  = d_in[16];
    const void* out_b  = d_in[17];

    // stage-2 chunking by available workspace (ws_size is host-visible)
    const int nb = (ws_size >= 81592320ull) ? 4
                 : (ws_size >= 48037888ull) ? 2 : 1;

    // ---- workspace layout ----
    char* ws = (char*)d_ws;
    int*   flag = (int*)  (ws + 0);
    u16*   wH   = (u16*)  (ws + 4096);        // 4608 B head weights
    u16*   wT1  = (u16*)  (ws + 65536);
    u16*   wT2  = (u16*)  (ws + 1245184);
    u16*   pwT  = (u16*)  (ws + 2424832);
    u16*   c1   = (u16*)  (ws + 3997696);     // 8 MB bf16 (4, 4096px, 256) ch-last
    float* o2   = (float*)(ws + 12386304);    // 2 MB f32 (4,32,64,64)
    u16*   up2c = (u16*)  (ws + 14483456);    // nb*8 MB bf16 blocked [8][16384][32]
    u16*   c2c  = (u16*)  (ws + 14483456 + (size_t)nb * 8388608);  // nb*8 MB
    float* gbuf = (float*)(ws + 3997696);     // 16 MB, dead before c1/o2/up1
    float* x0   = (float*)(ws + 20774912);    // 4 MB (dead before up2c/c2c)
    float* x1   = (float*)(ws + 24969216);    // 4 MB
    float* o1   = (float*)(ws + 29163520);    // 0.5 MB
    u16*   up1  = (u16*)  (ws + 12386304);    // 8 MB blocked [8][4096][32]

    // 0) dtype detect + weight transposes
    k_detect<<<1, 256, 0, stream>>>(f1, flag);
    k_wt<<<2304, 256, 0, stream>>>(cw1, wT1, flag);
    k_wt<<<2304, 256, 0, stream>>>(cw2, wT2, flag);
    k_pwt<<<3072, 256, 0, stream>>>(proj_w, pwT, flag);
    k_wh<<<9, 256, 0, stream>>>(out_w, wH, flag);

    // 1) weighted fusion (MFMA) -> gbuf, then sum -> x0 (channels-last)
    k_fgemm<<<dim3(2, 8, 16), 256, 0, stream>>>(f1, f2, f3, f4, pwT, lwp, flag, gbuf);
    k_fsum<<<4096, 256, 0, stream>>>(gbuf, x0);

    // 2) spatial detail enhancer -> x1 f32 (channels-last)
    k_dw<<<4096, 256, 0, stream>>>(x0, dw_w, bn_enh, flag, x1);

    // 3) dysample #1 (32->64, blocked out) + conv1 -> c1 ch-last (all 4 batches)
    k_offs<false><<<512, 256, 0, stream>>>(x1, ow1, ob1, flag, o1, 32 * 32);
    k_sample<false><<<16384, 256, 0, stream>>>(x1, o1, up1, 32, 32, 6);
    k_cb<6><<<dim3(2, 32, 4), 256, 0, stream>>>(up1, wT1, bn1, flag, c1, 64);

    // 4) offsets for stage 2 (all batches)
    k_offs<true><<<2048, 256, 0, stream>>>(c1, ow2, ob2, flag, o2, 64 * 64);

    // 5) chunked: dysample #2 (64->128, blocked out) + conv2 + head
    for (int b0 = 0; b0 < 4; b0 += nb) {
        const u16*   c1b = c1 + (size_t)b0 * 4096 * 256;
        const float* o2b = o2 + (size_t)b0 * 32 * 4096;
        k_sample<true><<<16384 * nb, 256, 0, stream>>>(c1b, o2b, up2c, 64, 64, 7);
        k_cb<7><<<dim3(2, 128, nb), 256, 0, stream>>>(up2c, wT2, bn2, flag,
                                                      c2c, 128);
        k_head<<<dim3(64, nb), 256, 0, stream>>>(c2c, wH, out_b, flag, d_out, b0);
    }
}